// Round 8
// baseline (666.282 us; speedup 1.0000x reference)
//
#include <hip/hip_runtime.h>
#include <math.h>

#define NB_IN   128
#define NBINS   39
#define NLM     400
#define NZO     512
#define NPAIR   780
#define NPACK   5530
#define TWOB    40
#define PI_D    3.14159265358979323846
#define SCALING 0.008164965809277261

__host__ __device__ __forceinline__ int loffd(int l){ return l*(4*l*l + 3*l - 1)/6; }

__device__ __forceinline__ int lidx(int lm){
  int l = (int)sqrtf((float)lm);
  while ((l+1)*(l+1) <= lm) ++l;
  while (l*l > lm) --l;
  return l;
}

// Wigner little-d via Jacobi sum (one-shot)
__device__ double wigner_d(int l, int m, int n, double beta, const double* lg){
  double cb = cos(0.5*beta), sb = sin(0.5*beta);
  double lcb = log(cb), lsb = log(sb);
  double pref = 0.5*(lg[l+m]+lg[l-m]+lg[l+n]+lg[l-n]);
  int s0 = 0 > (n-m) ? 0 : (n-m);
  int s1 = (l+n) < (l-m) ? (l+n) : (l-m);
  double val = 0.0;
  for (int s = s0; s <= s1; ++s){
    double c = pref - (lg[l+n-s]+lg[s]+lg[m-n+s]+lg[l-m-s]);
    double t = exp(c + (double)(2*l+n-m-2*s)*lcb + (double)(m-n+2*s)*lsb);
    val += ((m-n+s)&1) ? -t : t;
  }
  return val;
}

// fast Wigner: 2 log + 1 exp + ratio recurrence over s (fp64)
__device__ double wigner_fast(int l, int m, int n, double beta, const double* lg){
  double cb = cos(0.5*beta), sb = sin(0.5*beta);
  double lcb = log(cb), lsb = log(sb);
  double pref = 0.5*(lg[l+m]+lg[l-m]+lg[l+n]+lg[l-n]);
  int s0 = 0 > (n-m) ? 0 : (n-m);
  int s1 = (l+n) < (l-m) ? (l+n) : (l-m);
  double ratio = (sb*sb)/(cb*cb);
  double t = exp(pref - (lg[l+n-s0]+lg[s0]+lg[m-n+s0]+lg[l-m-s0])
               + (double)(2*l+n-m-2*s0)*lcb + (double)(m-n+2*s0)*lsb);
  double sgn = ((m-n+s0)&1) ? -1.0 : 1.0;
  double acc = 0.0;
  for (int s = s0; s <= s1; ++s){
    acc += sgn*t;
    sgn = -sgn;
    t *= ratio * ((double)((l+n-s)*(l-m-s)) / (double)((s+1)*(m-n+s+1)));
  }
  return acc;
}

// ---- constants -------------------------------------------------------
__global__ void k_init(double* lg, double* wq, int* ridx, int* psort){
  int t = threadIdx.x;  // 256
  if (t == 0){
    lg[0] = 0.0; double acc = 0.0;
    for (int k = 1; k <= 40; ++k){ acc += log((double)k); lg[k] = acc; }
  }
  for (int pair = t; pair < 210; pair += 256){
    int l = (int)((sqrtf(8.f*pair+1.f)-1.f)*0.5f);
    while ((l+1)*(l+2)/2 <= pair) ++l;
    while (l*(l+1)/2 > pair) --l;
    int mj = pair - l*(l+1)/2;
    int base = loffd(l) + mj*(2*l+1);
    for (int j = 0; j < 2*l+1; ++j){
      int njs = 19-l + j;
      ridx[base+j] = mj | (njs<<8) | (l<<16);
    }
  }
  for (int p = t; p < NPAIR; p += 256){
    int mj = p/39, njs = p%39, d = njs-19, ad = d<0?-d:d;
    int lam = mj > ad ? mj : ad;
    int pre = (lam==0) ? 0 : (2*lam-1)*lam;
    int rank = (mj < lam) ? (2*mj + ((njs==19+lam)?1:0))
                          : (2*lam + (njs-(19-lam)));
    psort[pre+rank] = mj | (njs<<8);
  }
  if (t < 128){
    double theta = PI_D*(2*t+1)/256.0;
    double s = 0.0;
    for (int k = 0; k < 64; ++k) s += sin((2*k+1)*theta)/(double)(2*k+1);
    wq[t] = (2.0/64.0)*sin(theta)*s;
  }
}

__global__ void k_wsyn(float2* wsyn){
  // wsyn[njs*40+g] = e^{ i (njs-19) g 2pi/40 };  Wm[mj][a] = wsyn[(19+mj)*40+a]
  for (int idx = threadIdx.x; idx < 1560; idx += 256){
    int njs = idx/40, g = idx%40;
    double ang = 2.0*PI_D*(double)(njs-19)*(double)g/40.0;
    wsyn[idx] = make_float2((float)cos(ang), (float)sin(ang));
  }
}

__global__ void k_ws2(float* w_s2, const double* lg, const double* wq){
  int tid = blockIdx.x*256 + threadIdx.x;
  if (tid >= 400*8) return;
  int lm = tid >> 3, bc = tid & 7;
  int l = lidx(lm); int m = lm - l*l - l;
  for (int j = 0; j < 16; ++j){
    int b = bc*16 + j;
    double beta = PI_D*(2*b+1)/256.0;
    w_s2[b*NLM + lm] = (float)(wigner_fast(l, m, 0, beta, lg) * wq[b]);
  }
}

__global__ void k_dinv2(float* dinv2, const int* ridx, const double* lg){
  int k = blockIdx.x*256 + threadIdx.x;
  if (k >= NPACK) return;
  int info = ridx[k];
  int mj = info & 255, n = ((info>>8)&255) - 19, l = info>>16;
  for (int b = 0; b < 20; ++b){
    double beta = PI_D*(2*b+1)/80.0;
    dinv2[b*NPACK + k] = (float)((double)(2*l+1) * wigner_fast(l, mj, n, beta, lg));
  }
}

__global__ void k_dmir(float* dinv2, const int* ridx){
  int tid = blockIdx.x*256 + threadIdx.x;
  if (tid >= 20*NPACK) return;
  int bb = tid / NPACK, k = tid % NPACK;
  int info = ridx[k];
  int mj = info & 255, njs = (info>>8)&255, l = info>>16;
  int srck = loffd(l) + mj*(2*l+1) + (l - (njs-19));
  float v = dinv2[(19-bb)*NPACK + srck];
  dinv2[(20+bb)*NPACK + k] = ((l+mj)&1) ? -v : v;
}

__global__ void k_Fc(float2* Fc, const double* lg){
  int tid = blockIdx.x*256 + threadIdx.x;
  if (tid >= 24*NLM) return;
  int p = tid / NLM, lm = tid % NLM;
  int l = lidx(lm); int m = lm - l*l - l;
  double beta = PI_D*(double)(p/8 + 1)/24.0;
  double alpha = (double)(p%8)*(PI_D/4.0);
  double d = wigner_d(l, m, 0, beta, lg);
  double a = (double)m*alpha;            // conj(F_k)
  Fc[tid] = make_float2((float)(d*cos(a)), (float)(d*sin(a)));
}

__global__ void k_yc(const float* ker, const float2* Fc, float2* ycT){
  int tid = blockIdx.x*256 + threadIdx.x;
  if (tid >= NLM*NZO) return;
  int lm = tid / 512, io = tid % 512;
  int i = io >> 5, o = io & 31;
  float2 acc = make_float2(0.f, 0.f);
  for (int p = 0; p < 24; ++p){
    float kv = ker[io*24 + p];
    float2 f = Fc[p*NLM + lm];
    acc.x += kv*f.x; acc.y += kv*f.y;
  }
  acc.x *= (float)SCALING; acc.y *= (float)SCALING;
  ycT[((size_t)(o*16 + i))*NLM + lm] = acc;
}

// ---- pipeline --------------------------------------------------------
__global__ __launch_bounds__(256) void k_dft(const float* x, float2* xf){
  __shared__ float rows[4][128];
  int t = threadIdx.x, g = t >> 6, lane = t & 63;
  int r = blockIdx.x*4 + g;
  int zi = r & 255, b = r >> 8;
  const float* xr = x + ((size_t)zi*128 + b)*128;
  rows[g][lane]    = xr[lane];
  rows[g][lane+64] = xr[lane+64];
  __syncthreads();
  if (lane < NBINS){
    int m = lane - 19;
    float ang = -2.0f*(float)PI_D*(float)m/128.0f;
    float sn, cs; sincosf(ang, &sn, &cs);
    float wr = 1.f, wi = 0.f;
    float2 acc = make_float2(0.f, 0.f);
    const float* rw = rows[g];
    #pragma unroll 8
    for (int a = 0; a < 128; ++a){
      float v = rw[a];
      acc.x += v*wr; acc.y += v*wi;
      float nr = wr*cs - wi*sn;
      wi = wr*sn + wi*cs; wr = nr;
    }
    xf[((size_t)lane*128 + b)*256 + zi] = acc;
  }
}

__global__ void k_xlp(const float2* xf, const float* w_s2, float2* xlp){
  int lm = blockIdx.x, c = blockIdx.y, zi = threadIdx.x;
  int l = lidx(lm); int m = lm - l*l - l;
  int bin = m + 19;
  float2 acc = make_float2(0.f, 0.f);
  for (int b = c*32; b < c*32+32; ++b){
    float w = w_s2[b*NLM + lm];
    float2 v = xf[((size_t)bin*128 + b)*256 + zi];
    acc.x += w*v.x; acc.y += w*v.y;
  }
  xlp[((size_t)(c*NLM + lm))*256 + zi] = acc;
}

__global__ void k_xlsum(const float2* xlp, float2* xlT){
  int lm = blockIdx.x, zi = threadIdx.x;
  float2 s = make_float2(0.f, 0.f);
  for (int c = 0; c < 4; ++c){
    float2 v = xlp[((size_t)(c*NLM + lm))*256 + zi];
    s.x += v.x; s.y += v.y;
  }
  xlT[(size_t)zi*NLM + lm] = s;
}

__global__ void k_zl2(const float2* xlT, const float2* ycT, const int* ridx, float2* zl2){
  int tid = blockIdx.x*256 + threadIdx.x;
  int zo = tid / NPACK, k = tid % NPACK;
  int info = ridx[k];
  int mj = info & 255, njs = (info>>8)&255, l = info>>16;
  int z = zo >> 5, o = zo & 31;
  int lmm = l*l + l + mj;
  int lmn = l*l + l + (njs - 19);
  float2 acc = make_float2(0.f, 0.f);
  for (int i = 0; i < 16; ++i){
    float2 a  = xlT[(size_t)(z*16 + i)*NLM + lmm];
    float2 bb = ycT[(size_t)(o*16 + i)*NLM + lmn];
    acc.x += a.x*bb.x - a.y*bb.y;
    acc.y += a.x*bb.y + a.y*bb.x;
  }
  zl2[tid] = acc;
}

// fused synthesis: block = (zo, 4 consecutive b), 512 threads, 2 barriers
__global__ __launch_bounds__(512) void k_syn7(const float2* zl2, const float* dinv2,
                                              const int* psort, const float2* wsyn,
                                              const float* bias, float* out){
  __shared__ float2 Cs[4*NPAIR];               // 24.96 KB
  __shared__ __align__(16) float2 Gs[4*800];   // 25.6 KB
  __shared__ __align__(16) float2 Wns[1560];   // 12.48 KB

  int bid = blockIdx.x;
  int blk = (bid & 7)*640 + (bid >> 3);   // 5120 blocks, XCD-contiguous zo runs
  int zo = blk / 10, bgrp = blk % 10;
  int b0 = bgrp*4;
  int o = zo & 31;
  int t = threadIdx.x;
  float bv = bias[o];

  for (int idx = t; idx < 1560; idx += 512) Wns[idx] = wsyn[idx];

  // ---- stage 1: Cs[b][pair] = sum_l dinv2[b][id]*zl2[zo][id] ----
  const float2* zrow = zl2 + (size_t)zo*NPACK;
  for (int idx = t; idx < 4*NPAIR; idx += 512){
    int b_ = idx & 3, p = idx >> 2;
    int pk = psort[p];
    int mj = pk & 255, njs = (pk>>8) & 255;
    int d_ = njs - 19, ad = d_ < 0 ? -d_ : d_;
    int lam = mj > ad ? mj : ad;
    const float* drow = dinv2 + (size_t)(b0 + b_)*NPACK;
    float2 acc = make_float2(0.f, 0.f);
    for (int l = lam; l < 20; ++l){
      int id = loffd(l) + mj*(2*l+1) + (njs - 19 + l);
      float dv = drow[id];
      float2 zv = zrow[id];
      acc.x += dv*zv.x; acc.y += dv*zv.y;
    }
    Cs[b_*NPAIR + mj*39 + njs] = acc;
  }
  __syncthreads();

  // ---- stage 2: Gs[b][mj][g] = sum_n Cs[b][mj][n]*Wn[n][g], 4mj x 2g tiles ----
  if (t < 400){
    int g2 = t % 20, r = t / 20;         // r = b*5 + mjc
    int b_ = r / 5, mjc = r % 5;
    const float2* crow = Cs + b_*NPAIR + (4*mjc)*39;
    float2 a00 = make_float2(0.f,0.f), a01 = a00, a10 = a00, a11 = a00;
    float2 a20 = a00, a21 = a00, a30 = a00, a31 = a00;
    for (int nj = 0; nj < 39; ++nj){
      float4 w = *(const float4*)&Wns[nj*40 + 2*g2];
      float2 c0 = crow[nj], c1 = crow[39+nj], c2 = crow[78+nj], c3 = crow[117+nj];
      a00.x += c0.x*w.x - c0.y*w.y; a00.y += c0.x*w.y + c0.y*w.x;
      a01.x += c0.x*w.z - c0.y*w.w; a01.y += c0.x*w.w + c0.y*w.z;
      a10.x += c1.x*w.x - c1.y*w.y; a10.y += c1.x*w.y + c1.y*w.x;
      a11.x += c1.x*w.z - c1.y*w.w; a11.y += c1.x*w.w + c1.y*w.z;
      a20.x += c2.x*w.x - c2.y*w.y; a20.y += c2.x*w.y + c2.y*w.x;
      a21.x += c2.x*w.z - c2.y*w.w; a21.y += c2.x*w.w + c2.y*w.z;
      a30.x += c3.x*w.x - c3.y*w.y; a30.y += c3.x*w.y + c3.y*w.x;
      a31.x += c3.x*w.z - c3.y*w.w; a31.y += c3.x*w.w + c3.y*w.z;
    }
    float2* gb = Gs + b_*800;
    *(float4*)&gb[(4*mjc+0)*40 + 2*g2] = make_float4(a00.x,a00.y,a01.x,a01.y);
    *(float4*)&gb[(4*mjc+1)*40 + 2*g2] = make_float4(a10.x,a10.y,a11.x,a11.y);
    *(float4*)&gb[(4*mjc+2)*40 + 2*g2] = make_float4(a20.x,a20.y,a21.x,a21.y);
    *(float4*)&gb[(4*mjc+3)*40 + 2*g2] = make_float4(a30.x,a30.y,a31.x,a31.y);
  }
  __syncthreads();

  // ---- stage 3: out[b][a][g] = Gs[b][0][g].x + 2*sum_{mj>=1} Re(Gs[b][mj][g]*Wm[mj][a]) + bias
  for (int idx = t; idx < 800; idx += 512){
    int g2 = idx % 20, r = idx / 20;     // r = b*10 + ac
    int b_ = r / 10, ac = r % 10;
    const float2* gb = Gs + b_*800;
    float s00=0.f,s01=0.f,s10=0.f,s11=0.f,s20=0.f,s21=0.f,s30=0.f,s31=0.f;
    for (int mj = 1; mj < 20; ++mj){
      float4 gv = *(const float4*)&gb[mj*40 + 2*g2];          // G[g0], G[g1]
      float4 wA = *(const float4*)&Wns[(19+mj)*40 + 4*ac];    // Wm[a0], Wm[a1]
      float4 wB = *(const float4*)&Wns[(19+mj)*40 + 4*ac + 2];// Wm[a2], Wm[a3]
      s00 += gv.x*wA.x - gv.y*wA.y;  s01 += gv.z*wA.x - gv.w*wA.y;
      s10 += gv.x*wA.z - gv.y*wA.w;  s11 += gv.z*wA.z - gv.w*wA.w;
      s20 += gv.x*wB.x - gv.y*wB.y;  s21 += gv.z*wB.x - gv.w*wB.y;
      s30 += gv.x*wB.z - gv.y*wB.w;  s31 += gv.z*wB.z - gv.w*wB.w;
    }
    float g0a = gb[2*g2].x, g0b = gb[2*g2+1].x;
    float* orow = out + ((size_t)zo*40 + b0 + b_)*1600;
    *(float2*)&orow[(4*ac+0)*40 + 2*g2] = make_float2(g0a + 2.f*s00 + bv, g0b + 2.f*s01 + bv);
    *(float2*)&orow[(4*ac+1)*40 + 2*g2] = make_float2(g0a + 2.f*s10 + bv, g0b + 2.f*s11 + bv);
    *(float2*)&orow[(4*ac+2)*40 + 2*g2] = make_float2(g0a + 2.f*s20 + bv, g0b + 2.f*s21 + bv);
    *(float2*)&orow[(4*ac+3)*40 + 2*g2] = make_float2(g0a + 2.f*s30 + bv, g0b + 2.f*s31 + bv);
  }
}

extern "C" void kernel_launch(void* const* d_in, const int* in_sizes, int n_in,
                              void* d_out, int out_size, void* d_ws, size_t ws_size,
                              hipStream_t stream) {
  const float* x    = (const float*)d_in[0];
  const float* ker  = (const float*)d_in[1];
  const float* bias = (const float*)d_in[2];
  float* out = (float*)d_out;

  char* ws = (char*)d_ws;
  size_t cur = 0;
  auto alloc = [&](size_t bytes)->char*{
    char* p = ws + cur;
    cur += (bytes + 255) & ~(size_t)255;
    return p;
  };
  double* lg    = (double*)alloc(64*8);
  double* wq    = (double*)alloc(128*8);
  int*    ridx  = (int*)   alloc(NPACK*4);
  int*    psort = (int*)   alloc(NPAIR*4);
  float2* wsyn  = (float2*)alloc((size_t)1560*8);
  float*  w_s2  = (float*) alloc((size_t)NB_IN*NLM*4);
  float*  dinv2 = (float*) alloc((size_t)TWOB*NPACK*4);
  float2* Fc    = (float2*)alloc((size_t)24*NLM*8);
  float2* ycT   = (float2*)alloc((size_t)512*400*8);
  float2* xf    = (float2*)alloc((size_t)NBINS*128*256*8);
  float2* xlp   = (float2*)alloc((size_t)4*NLM*256*8);
  float2* xlT   = (float2*)alloc((size_t)256*NLM*8);
  float2* zl2   = (float2*)alloc((size_t)NZO*NPACK*8);
  (void)ws_size; (void)in_sizes; (void)n_in; (void)out_size;

  k_init <<<1, 256, 0, stream>>>(lg, wq, ridx, psort);
  k_wsyn <<<1, 256, 0, stream>>>(wsyn);
  k_ws2  <<<13, 256, 0, stream>>>(w_s2, lg, wq);
  k_dinv2<<<22, 256, 0, stream>>>(dinv2, ridx, lg);
  k_dmir <<<(20*NPACK + 255)/256, 256, 0, stream>>>(dinv2, ridx);
  k_Fc   <<<38, 256, 0, stream>>>(Fc, lg);
  k_yc   <<<800, 256, 0, stream>>>(ker, Fc, ycT);

  k_dft  <<<(256*128)/4, 256, 0, stream>>>(x, xf);
  k_xlp  <<<dim3(NLM, 4), 256, 0, stream>>>(xf, w_s2, xlp);
  k_xlsum<<<NLM, 256, 0, stream>>>(xlp, xlT);
  k_zl2  <<<(NZO*NPACK)/256, 256, 0, stream>>>(xlT, ycT, ridx, zl2);
  k_syn7 <<<5120, 512, 0, stream>>>(zl2, dinv2, psort, wsyn, bias, out);
}

// Round 9
// 639.706 us; speedup vs baseline: 1.0415x; 1.0415x over previous
//
#include <hip/hip_runtime.h>
#include <math.h>

#define NB_IN   128
#define NBINS   39
#define NLM     400
#define NZO     512
#define NPAIR   780
#define NPACK   5530
#define TWOB    40
#define PI_D    3.14159265358979323846
#define SCALING 0.008164965809277261

__host__ __device__ __forceinline__ int loffd(int l){ return l*(4*l*l + 3*l - 1)/6; }

__device__ __forceinline__ int lidx(int lm){
  int l = (int)sqrtf((float)lm);
  while ((l+1)*(l+1) <= lm) ++l;
  while (l*l > lm) --l;
  return l;
}

// Wigner little-d via Jacobi sum (one-shot)
__device__ double wigner_d(int l, int m, int n, double beta, const double* lg){
  double cb = cos(0.5*beta), sb = sin(0.5*beta);
  double lcb = log(cb), lsb = log(sb);
  double pref = 0.5*(lg[l+m]+lg[l-m]+lg[l+n]+lg[l-n]);
  int s0 = 0 > (n-m) ? 0 : (n-m);
  int s1 = (l+n) < (l-m) ? (l+n) : (l-m);
  double val = 0.0;
  for (int s = s0; s <= s1; ++s){
    double c = pref - (lg[l+n-s]+lg[s]+lg[m-n+s]+lg[l-m-s]);
    double t = exp(c + (double)(2*l+n-m-2*s)*lcb + (double)(m-n+2*s)*lsb);
    val += ((m-n+s)&1) ? -t : t;
  }
  return val;
}

// fast Wigner: 2 log + 1 exp + ratio recurrence over s (fp64)
__device__ double wigner_fast(int l, int m, int n, double beta, const double* lg){
  double cb = cos(0.5*beta), sb = sin(0.5*beta);
  double lcb = log(cb), lsb = log(sb);
  double pref = 0.5*(lg[l+m]+lg[l-m]+lg[l+n]+lg[l-n]);
  int s0 = 0 > (n-m) ? 0 : (n-m);
  int s1 = (l+n) < (l-m) ? (l+n) : (l-m);
  double ratio = (sb*sb)/(cb*cb);
  double t = exp(pref - (lg[l+n-s0]+lg[s0]+lg[m-n+s0]+lg[l-m-s0])
               + (double)(2*l+n-m-2*s0)*lcb + (double)(m-n+2*s0)*lsb);
  double sgn = ((m-n+s0)&1) ? -1.0 : 1.0;
  double acc = 0.0;
  for (int s = s0; s <= s1; ++s){
    acc += sgn*t;
    sgn = -sgn;
    t *= ratio * ((double)((l+n-s)*(l-m-s)) / (double)((s+1)*(m-n+s+1)));
  }
  return acc;
}

// ---- constants: k_init (lg, wq, ridx, psort, wsyn) -------------------
__global__ void k_init(double* lg, double* wq, int* ridx, int* psort, float2* wsyn){
  int t = threadIdx.x;  // 256
  if (t == 0){
    lg[0] = 0.0; double acc = 0.0;
    for (int k = 1; k <= 40; ++k){ acc += log((double)k); lg[k] = acc; }
  }
  for (int pair = t; pair < 210; pair += 256){
    int l = (int)((sqrtf(8.f*pair+1.f)-1.f)*0.5f);
    while ((l+1)*(l+2)/2 <= pair) ++l;
    while (l*(l+1)/2 > pair) --l;
    int mj = pair - l*(l+1)/2;
    int base = loffd(l) + mj*(2*l+1);
    for (int j = 0; j < 2*l+1; ++j){
      int njs = 19-l + j;
      ridx[base+j] = mj | (njs<<8) | (l<<16);
    }
  }
  for (int p = t; p < NPAIR; p += 256){
    int mj = p/39, njs = p%39, d = njs-19, ad = d<0?-d:d;
    int lam = mj > ad ? mj : ad;
    int pre = (lam==0) ? 0 : (2*lam-1)*lam;
    int rank = (mj < lam) ? (2*mj + ((njs==19+lam)?1:0))
                          : (2*lam + (njs-(19-lam)));
    psort[pre+rank] = mj | (njs<<8);
  }
  if (t < 128){
    double theta = PI_D*(2*t+1)/256.0;
    double s = 0.0;
    for (int k = 0; k < 64; ++k) s += sin((2*k+1)*theta)/(double)(2*k+1);
    wq[t] = (2.0/64.0)*sin(theta)*s;
  }
  // wsyn[njs*40+g] = e^{i (njs-19) g 2pi/40}; Wm[mj][a] = wsyn[(19+mj)*40+a]
  for (int idx = t; idx < 1560; idx += 256){
    int njs = idx/40, g = idx%40;
    double ang = 2.0*PI_D*(double)(njs-19)*(double)g/40.0;
    wsyn[idx] = make_float2((float)cos(ang), (float)sin(ang));
  }
}

// ---- fused tables: blocks 0..12 ws2 | 13..34 dinv2(+mirror) | 35..72 Fc
__global__ void k_tables(float* w_s2, float* dinv2, float2* Fc,
                         const int* ridx, const double* lg, const double* wq){
  int bid = blockIdx.x, t = threadIdx.x;
  if (bid < 13){
    int tid = bid*256 + t;
    if (tid >= 400*8) return;
    int lm = tid >> 3, bc = tid & 7;
    int l = lidx(lm); int m = lm - l*l - l;
    for (int j = 0; j < 16; ++j){
      int b = bc*16 + j;
      double beta = PI_D*(2*b+1)/256.0;
      w_s2[b*NLM + lm] = (float)(wigner_fast(l, m, 0, beta, lg) * wq[b]);
    }
  } else if (bid < 35){
    int k = (bid-13)*256 + t;
    if (k >= NPACK) return;
    int info = ridx[k];
    int mj = info & 255, njs = (info>>8)&255, l = info>>16;
    int n = njs - 19;
    int mirror_k = loffd(l) + mj*(2*l+1) + (l + 19 - njs);
    float sgn = ((l+mj)&1) ? -1.f : 1.f;
    for (int b = 0; b < 20; ++b){
      double beta = PI_D*(2*b+1)/80.0;
      float v = (float)((double)(2*l+1) * wigner_fast(l, mj, n, beta, lg));
      dinv2[b*NPACK + k] = v;
      dinv2[(39-b)*NPACK + mirror_k] = sgn * v;   // d(pi-b) identity
    }
  } else {
    int tid = (bid-35)*256 + t;
    if (tid >= 24*NLM) return;
    int p = tid / NLM, lm = tid % NLM;
    int l = lidx(lm); int m = lm - l*l - l;
    double beta = PI_D*(double)(p/8 + 1)/24.0;
    double alpha = (double)(p%8)*(PI_D/4.0);
    double d = wigner_d(l, m, 0, beta, lg);
    double a = (double)m*alpha;            // conj(F_k)
    Fc[tid] = make_float2((float)(d*cos(a)), (float)(d*sin(a)));
  }
}

__global__ void k_yc(const float* ker, const float2* Fc, float2* ycT){
  int tid = blockIdx.x*256 + threadIdx.x;
  if (tid >= NLM*NZO) return;
  int lm = tid / 512, io = tid % 512;
  int i = io >> 5, o = io & 31;
  float2 acc = make_float2(0.f, 0.f);
  for (int p = 0; p < 24; ++p){
    float kv = ker[io*24 + p];
    float2 f = Fc[p*NLM + lm];
    acc.x += kv*f.x; acc.y += kv*f.y;
  }
  acc.x *= (float)SCALING; acc.y *= (float)SCALING;
  ycT[((size_t)(o*16 + i))*NLM + lm] = acc;
}

// ---- pipeline --------------------------------------------------------
// xf[mj][b][zi]; 4-way ILP phase recurrence (chain 128 -> 32)
__global__ __launch_bounds__(256) void k_dft(const float* x, float2* xf){
  __shared__ float rows[4][128];
  int t = threadIdx.x, g = t >> 6, lane = t & 63;
  int r = blockIdx.x*4 + g;
  int zi = r & 255, b = r >> 8;
  const float* xr = x + ((size_t)zi*128 + b)*128;
  rows[g][lane]    = xr[lane];
  rows[g][lane+64] = xr[lane+64];
  __syncthreads();
  if (lane < NBINS){
    int m = lane - 19;
    float th = -2.0f*(float)PI_D*(float)m/128.0f;
    float sn1, cs1; sincosf(th, &sn1, &cs1);
    float cs2 = cs1*cs1 - sn1*sn1, sn2 = 2.f*cs1*sn1;
    float cs4 = cs2*cs2 - sn2*sn2, sn4 = 2.f*cs2*sn2;
    float w0r = 1.f, w0i = 0.f;
    float w1r = cs1, w1i = sn1;
    float w2r = cs2, w2i = sn2;
    float w3r = cs1*cs2 - sn1*sn2, w3i = cs1*sn2 + sn1*cs2;
    float2 a0 = make_float2(0.f,0.f), a1 = a0, a2 = a0, a3 = a0;
    const float* rw = rows[g];
    #pragma unroll 4
    for (int q = 0; q < 32; ++q){
      float v0 = rw[4*q], v1 = rw[4*q+1], v2 = rw[4*q+2], v3 = rw[4*q+3];
      a0.x += v0*w0r; a0.y += v0*w0i;
      a1.x += v1*w1r; a1.y += v1*w1i;
      a2.x += v2*w2r; a2.y += v2*w2i;
      a3.x += v3*w3r; a3.y += v3*w3i;
      float nr;
      nr = w0r*cs4 - w0i*sn4; w0i = w0r*sn4 + w0i*cs4; w0r = nr;
      nr = w1r*cs4 - w1i*sn4; w1i = w1r*sn4 + w1i*cs4; w1r = nr;
      nr = w2r*cs4 - w2i*sn4; w2i = w2r*sn4 + w2i*cs4; w2r = nr;
      nr = w3r*cs4 - w3i*sn4; w3i = w3r*sn4 + w3i*cs4; w3r = nr;
    }
    float2 acc = make_float2(a0.x+a1.x+a2.x+a3.x, a0.y+a1.y+a2.y+a3.y);
    xf[((size_t)lane*128 + b)*256 + zi] = acc;
  }
}

// xlT[zi][lm] = sum_b w_s2[b][lm] * xf[bin(lm)][b][zi]  (merged xlp+xlsum)
__global__ void k_xl(const float2* xf, const float* w_s2, float2* xlT){
  int lm = blockIdx.x, zi = threadIdx.x;
  int l = lidx(lm); int m = lm - l*l - l;
  int bin = m + 19;
  float2 acc = make_float2(0.f, 0.f);
  #pragma unroll 8
  for (int b = 0; b < 128; ++b){
    float w = w_s2[b*NLM + lm];
    float2 v = xf[((size_t)bin*128 + b)*256 + zi];
    acc.x += w*v.x; acc.y += w*v.y;
  }
  xlT[(size_t)zi*NLM + lm] = acc;
}

__global__ void k_zl2(const float2* xlT, const float2* ycT, const int* ridx, float2* zl2){
  int tid = blockIdx.x*256 + threadIdx.x;
  int zo = tid / NPACK, k = tid % NPACK;
  int info = ridx[k];
  int mj = info & 255, njs = (info>>8)&255, l = info>>16;
  int z = zo >> 5, o = zo & 31;
  int lmm = l*l + l + mj;
  int lmn = l*l + l + (njs - 19);
  float2 acc = make_float2(0.f, 0.f);
  for (int i = 0; i < 16; ++i){
    float2 a  = xlT[(size_t)(z*16 + i)*NLM + lmm];
    float2 bb = ycT[(size_t)(o*16 + i)*NLM + lmn];
    acc.x += a.x*bb.x - a.y*bb.y;
    acc.y += a.x*bb.y + a.y*bb.x;
  }
  zl2[tid] = acc;
}

// fused synthesis: block = (zo, 8 consecutive b), 512 threads
__global__ __launch_bounds__(512) void k_syn8(const float2* zl2, const float* dinv2,
                                              const int* psort, const float2* wsyn,
                                              const float* bias, float* out){
  __shared__ float2 zS[NPACK];               // 44.24 KB
  __shared__ float2 Cs[NPAIR];               // 6.24 KB
  __shared__ __align__(16) float2 Gs[800];   // 6.4 KB
  __shared__ __align__(16) float2 Wns[1560]; // 12.48 KB -> 67.7 KB total

  int bid = blockIdx.x;
  int blk = (bid & 7)*320 + (bid >> 3);   // 2560 blocks, XCD-contiguous
  int zo = blk / 5, bgrp = blk % 5;
  int b0 = bgrp*8;
  int o = zo & 31;
  int t = threadIdx.x;

  const float2* zrow = zl2 + (size_t)zo*NPACK;
  for (int k = t; k < NPACK; k += 512) zS[k] = zrow[k];
  for (int idx = t; idx < 1560; idx += 512) Wns[idx] = wsyn[idx];

  int pk0 = psort[t];
  int pk1 = psort[(t < NPAIR-512) ? (512+t) : 0];
  int mj0 = pk0&255, nj0 = (pk0>>8)&255;
  int mj1 = pk1&255, nj1 = (pk1>>8)&255;
  __syncthreads();

  float bv = bias[o];

  for (int bb = 0; bb < 8; ++bb){
    int b = b0 + bb;
    const float* drow = dinv2 + (size_t)b*NPACK;

    // ---- stage 1: C[pair] = sum_l d[b][id] * zS[id] ----
    float2 c0 = make_float2(0.f,0.f), c1 = c0;
    #pragma unroll
    for (int l = 0; l < 20; ++l){
      int W = 2*l+1;
      int base = loffd(l) + l - 19;     // id = base + mj*W + njs
      int np = (2*l+1)*(l+1);           // active-prefix closed form
      if (t < np){
        int id = base + mj0*W + nj0;
        float dv = drow[id]; float2 zv = zS[id];
        c0.x += dv*zv.x; c0.y += dv*zv.y;
      }
      if (512+t < np){
        int id = base + mj1*W + nj1;
        float dv = drow[id]; float2 zv = zS[id];
        c1.x += dv*zv.x; c1.y += dv*zv.y;
      }
    }
    Cs[mj0*39 + nj0] = c0;
    if (t < NPAIR-512) Cs[mj1*39 + nj1] = c1;
    __syncthreads();

    // ---- stage 2: G[mj][g] = sum_n C[mj][n]*Wn[n][g]; t<400: 2mj x 1g ----
    if (t < 400){
      int g = t % 40, mj2 = t / 40;      // mj2 in 0..9, 2 mj each
      const float2* crowA = Cs + (2*mj2)*39;
      const float2* crowB = crowA + 39;
      float2 aA = make_float2(0.f,0.f), aB = aA;
      for (int nj = 0; nj < 39; ++nj){
        float2 w  = Wns[nj*40 + g];
        float2 cA = crowA[nj];
        float2 cB = crowB[nj];
        aA.x += cA.x*w.x - cA.y*w.y; aA.y += cA.x*w.y + cA.y*w.x;
        aB.x += cB.x*w.x - cB.y*w.y; aB.y += cB.x*w.y + cB.y*w.x;
      }
      Gs[(2*mj2+0)*40 + g] = aA;
      Gs[(2*mj2+1)*40 + g] = aB;
    }
    __syncthreads();

    // ---- stage 3: out[a][g] = G0[g].x + 2*sum_{mj>=1} Re(G[mj][g]*Wm[mj][a]) + bias
    // t<400: 2a x 2g tiles, b128 LDS reads
    if (t < 400){
      int g2 = t % 20, ac = t / 20;      // ac in 0..19 (a pairs)
      float s00=0.f,s01=0.f,s10=0.f,s11=0.f;
      for (int mj = 1; mj < 20; ++mj){
        float4 gv = *(const float4*)&Gs[mj*40 + 2*g2];        // G[g0],G[g1]
        float4 wm = *(const float4*)&Wns[(19+mj)*40 + 2*ac];  // Wm[a0],Wm[a1]
        s00 += gv.x*wm.x - gv.y*wm.y;  s01 += gv.z*wm.x - gv.w*wm.y;
        s10 += gv.x*wm.z - gv.y*wm.w;  s11 += gv.z*wm.z - gv.w*wm.w;
      }
      float g0a = Gs[2*g2].x, g0b = Gs[2*g2+1].x;
      float* orow = out + ((size_t)zo*40 + b)*1600;
      *(float2*)&orow[(2*ac+0)*40 + 2*g2] = make_float2(g0a + 2.f*s00 + bv, g0b + 2.f*s01 + bv);
      *(float2*)&orow[(2*ac+1)*40 + 2*g2] = make_float2(g0a + 2.f*s10 + bv, g0b + 2.f*s11 + bv);
    }
    // no sync: stage3 reads Gs/Wns; next stage1 writes Cs only (disjoint);
    // next stage2's Gs writes are fenced by next stage1's __syncthreads
  }
}

extern "C" void kernel_launch(void* const* d_in, const int* in_sizes, int n_in,
                              void* d_out, int out_size, void* d_ws, size_t ws_size,
                              hipStream_t stream) {
  const float* x    = (const float*)d_in[0];
  const float* ker  = (const float*)d_in[1];
  const float* bias = (const float*)d_in[2];
  float* out = (float*)d_out;

  char* ws = (char*)d_ws;
  size_t cur = 0;
  auto alloc = [&](size_t bytes)->char*{
    char* p = ws + cur;
    cur += (bytes + 255) & ~(size_t)255;
    return p;
  };
  double* lg    = (double*)alloc(64*8);
  double* wq    = (double*)alloc(128*8);
  int*    ridx  = (int*)   alloc(NPACK*4);
  int*    psort = (int*)   alloc(NPAIR*4);
  float2* wsyn  = (float2*)alloc((size_t)1560*8);
  float*  w_s2  = (float*) alloc((size_t)NB_IN*NLM*4);
  float*  dinv2 = (float*) alloc((size_t)TWOB*NPACK*4);
  float2* Fc    = (float2*)alloc((size_t)24*NLM*8);
  float2* ycT   = (float2*)alloc((size_t)512*400*8);
  float2* xf    = (float2*)alloc((size_t)NBINS*128*256*8);
  float2* xlT   = (float2*)alloc((size_t)256*NLM*8);
  float2* zl2   = (float2*)alloc((size_t)NZO*NPACK*8);
  (void)ws_size; (void)in_sizes; (void)n_in; (void)out_size;

  k_init  <<<1, 256, 0, stream>>>(lg, wq, ridx, psort, wsyn);
  k_tables<<<73, 256, 0, stream>>>(w_s2, dinv2, Fc, ridx, lg, wq);
  k_yc    <<<800, 256, 0, stream>>>(ker, Fc, ycT);

  k_dft  <<<(256*128)/4, 256, 0, stream>>>(x, xf);
  k_xl   <<<NLM, 256, 0, stream>>>(xf, w_s2, xlT);
  k_zl2  <<<(NZO*NPACK)/256, 256, 0, stream>>>(xlT, ycT, ridx, zl2);
  k_syn8 <<<2560, 512, 0, stream>>>(zl2, dinv2, psort, wsyn, bias, out);
}

// Round 10
// 613.456 us; speedup vs baseline: 1.0861x; 1.0428x over previous
//
#include <hip/hip_runtime.h>
#include <math.h>

#define NB_IN   128
#define NBINS   39
#define NLM     400
#define NZO     512
#define NPAIR   780
#define NPACK   5530
#define TWOB    40
#define PI_D    3.14159265358979323846
#define SCALING 0.008164965809277261

__host__ __device__ __forceinline__ int loffd(int l){ return l*(4*l*l + 3*l - 1)/6; }

__device__ __forceinline__ int lidx(int lm){
  int l = (int)sqrtf((float)lm);
  while ((l+1)*(l+1) <= lm) ++l;
  while (l*l > lm) --l;
  return l;
}

// Wigner little-d via Jacobi sum (one-shot)
__device__ double wigner_d(int l, int m, int n, double beta, const double* lg){
  double cb = cos(0.5*beta), sb = sin(0.5*beta);
  double lcb = log(cb), lsb = log(sb);
  double pref = 0.5*(lg[l+m]+lg[l-m]+lg[l+n]+lg[l-n]);
  int s0 = 0 > (n-m) ? 0 : (n-m);
  int s1 = (l+n) < (l-m) ? (l+n) : (l-m);
  double val = 0.0;
  for (int s = s0; s <= s1; ++s){
    double c = pref - (lg[l+n-s]+lg[s]+lg[m-n+s]+lg[l-m-s]);
    double t = exp(c + (double)(2*l+n-m-2*s)*lcb + (double)(m-n+2*s)*lsb);
    val += ((m-n+s)&1) ? -t : t;
  }
  return val;
}

// fast Wigner: 2 log + 1 exp + ratio recurrence over s (fp64)
__device__ double wigner_fast(int l, int m, int n, double beta, const double* lg){
  double cb = cos(0.5*beta), sb = sin(0.5*beta);
  double lcb = log(cb), lsb = log(sb);
  double pref = 0.5*(lg[l+m]+lg[l-m]+lg[l+n]+lg[l-n]);
  int s0 = 0 > (n-m) ? 0 : (n-m);
  int s1 = (l+n) < (l-m) ? (l+n) : (l-m);
  double ratio = (sb*sb)/(cb*cb);
  double t = exp(pref - (lg[l+n-s0]+lg[s0]+lg[m-n+s0]+lg[l-m-s0])
               + (double)(2*l+n-m-2*s0)*lcb + (double)(m-n+2*s0)*lsb);
  double sgn = ((m-n+s0)&1) ? -1.0 : 1.0;
  double acc = 0.0;
  for (int s = s0; s <= s1; ++s){
    acc += sgn*t;
    sgn = -sgn;
    t *= ratio * ((double)((l+n-s)*(l-m-s)) / (double)((s+1)*(m-n+s+1)));
  }
  return acc;
}

// ---- constants: k_init (lg, wq, ridx, psort, wsyn) -------------------
__global__ void k_init(double* lg, double* wq, int* ridx, int* psort, float2* wsyn){
  int t = threadIdx.x;  // 256
  if (t == 0){
    lg[0] = 0.0; double acc = 0.0;
    for (int k = 1; k <= 40; ++k){ acc += log((double)k); lg[k] = acc; }
  }
  for (int pair = t; pair < 210; pair += 256){
    int l = (int)((sqrtf(8.f*pair+1.f)-1.f)*0.5f);
    while ((l+1)*(l+2)/2 <= pair) ++l;
    while (l*(l+1)/2 > pair) --l;
    int mj = pair - l*(l+1)/2;
    int base = loffd(l) + mj*(2*l+1);
    for (int j = 0; j < 2*l+1; ++j){
      int njs = 19-l + j;
      ridx[base+j] = mj | (njs<<8) | (l<<16);
    }
  }
  for (int p = t; p < NPAIR; p += 256){
    int mj = p/39, njs = p%39, d = njs-19, ad = d<0?-d:d;
    int lam = mj > ad ? mj : ad;
    int pre = (lam==0) ? 0 : (2*lam-1)*lam;
    int rank = (mj < lam) ? (2*mj + ((njs==19+lam)?1:0))
                          : (2*lam + (njs-(19-lam)));
    psort[pre+rank] = mj | (njs<<8);
  }
  if (t < 128){
    double theta = PI_D*(2*t+1)/256.0;
    double s = 0.0;
    for (int k = 0; k < 64; ++k) s += sin((2*k+1)*theta)/(double)(2*k+1);
    wq[t] = (2.0/64.0)*sin(theta)*s;
  }
  // wsyn[njs*40+g] = e^{i (njs-19) g 2pi/40}; Wm[mj][a] = wsyn[(19+mj)*40+a]
  for (int idx = t; idx < 1560; idx += 256){
    int njs = idx/40, g = idx%40;
    double ang = 2.0*PI_D*(double)(njs-19)*(double)g/40.0;
    wsyn[idx] = make_float2((float)cos(ang), (float)sin(ang));
  }
}

// ---- fused tables: blocks 0..12 ws2 | 13..34 dinv2(+mirror) | 35..72 Fc
__global__ void k_tables(float* w_s2, float* dinv2, float2* Fc,
                         const int* ridx, const double* lg, const double* wq){
  int bid = blockIdx.x, t = threadIdx.x;
  if (bid < 13){
    int tid = bid*256 + t;
    if (tid >= 400*8) return;
    int lm = tid >> 3, bc = tid & 7;
    int l = lidx(lm); int m = lm - l*l - l;
    for (int j = 0; j < 16; ++j){
      int b = bc*16 + j;
      double beta = PI_D*(2*b+1)/256.0;
      w_s2[b*NLM + lm] = (float)(wigner_fast(l, m, 0, beta, lg) * wq[b]);
    }
  } else if (bid < 35){
    int k = (bid-13)*256 + t;
    if (k >= NPACK) return;
    int info = ridx[k];
    int mj = info & 255, njs = (info>>8)&255, l = info>>16;
    int n = njs - 19;
    int mirror_k = loffd(l) + mj*(2*l+1) + (l + 19 - njs);
    float sgn = ((l+mj)&1) ? -1.f : 1.f;
    for (int b = 0; b < 20; ++b){
      double beta = PI_D*(2*b+1)/80.0;
      float v = (float)((double)(2*l+1) * wigner_fast(l, mj, n, beta, lg));
      dinv2[b*NPACK + k] = v;
      dinv2[(39-b)*NPACK + mirror_k] = sgn * v;   // d(pi-b) identity
    }
  } else {
    int tid = (bid-35)*256 + t;
    if (tid >= 24*NLM) return;
    int p = tid / NLM, lm = tid % NLM;
    int l = lidx(lm); int m = lm - l*l - l;
    double beta = PI_D*(double)(p/8 + 1)/24.0;
    double alpha = (double)(p%8)*(PI_D/4.0);
    double d = wigner_d(l, m, 0, beta, lg);
    double a = (double)m*alpha;            // conj(F_k)
    Fc[tid] = make_float2((float)(d*cos(a)), (float)(d*sin(a)));
  }
}

__global__ void k_yc(const float* ker, const float2* Fc, float2* ycT){
  int tid = blockIdx.x*256 + threadIdx.x;
  if (tid >= NLM*NZO) return;
  int lm = tid / 512, io = tid % 512;
  int i = io >> 5, o = io & 31;
  float2 acc = make_float2(0.f, 0.f);
  for (int p = 0; p < 24; ++p){
    float kv = ker[io*24 + p];
    float2 f = Fc[p*NLM + lm];
    acc.x += kv*f.x; acc.y += kv*f.y;
  }
  acc.x *= (float)SCALING; acc.y *= (float)SCALING;
  ycT[((size_t)(o*16 + i))*NLM + lm] = acc;
}

// ---- pipeline --------------------------------------------------------
// xf[mj][b][zi]; 4-way ILP phase recurrence
__global__ __launch_bounds__(256) void k_dft(const float* x, float2* xf){
  __shared__ float rows[4][128];
  int t = threadIdx.x, g = t >> 6, lane = t & 63;
  int r = blockIdx.x*4 + g;
  int zi = r & 255, b = r >> 8;
  const float* xr = x + ((size_t)zi*128 + b)*128;
  rows[g][lane]    = xr[lane];
  rows[g][lane+64] = xr[lane+64];
  __syncthreads();
  if (lane < NBINS){
    int m = lane - 19;
    float th = -2.0f*(float)PI_D*(float)m/128.0f;
    float sn1, cs1; sincosf(th, &sn1, &cs1);
    float cs2 = cs1*cs1 - sn1*sn1, sn2 = 2.f*cs1*sn1;
    float cs4 = cs2*cs2 - sn2*sn2, sn4 = 2.f*cs2*sn2;
    float w0r = 1.f, w0i = 0.f;
    float w1r = cs1, w1i = sn1;
    float w2r = cs2, w2i = sn2;
    float w3r = cs1*cs2 - sn1*sn2, w3i = cs1*sn2 + sn1*cs2;
    float2 a0 = make_float2(0.f,0.f), a1 = a0, a2 = a0, a3 = a0;
    const float* rw = rows[g];
    #pragma unroll 4
    for (int q = 0; q < 32; ++q){
      float v0 = rw[4*q], v1 = rw[4*q+1], v2 = rw[4*q+2], v3 = rw[4*q+3];
      a0.x += v0*w0r; a0.y += v0*w0i;
      a1.x += v1*w1r; a1.y += v1*w1i;
      a2.x += v2*w2r; a2.y += v2*w2i;
      a3.x += v3*w3r; a3.y += v3*w3i;
      float nr;
      nr = w0r*cs4 - w0i*sn4; w0i = w0r*sn4 + w0i*cs4; w0r = nr;
      nr = w1r*cs4 - w1i*sn4; w1i = w1r*sn4 + w1i*cs4; w1r = nr;
      nr = w2r*cs4 - w2i*sn4; w2i = w2r*sn4 + w2i*cs4; w2r = nr;
      nr = w3r*cs4 - w3i*sn4; w3i = w3r*sn4 + w3i*cs4; w3r = nr;
    }
    float2 acc = make_float2(a0.x+a1.x+a2.x+a3.x, a0.y+a1.y+a2.y+a3.y);
    xf[((size_t)lane*128 + b)*256 + zi] = acc;
  }
}

// xlT[zi][lm] = sum_b w_s2[b][lm] * xf[bin(lm)][b][zi]
__global__ void k_xl(const float2* xf, const float* w_s2, float2* xlT){
  int lm = blockIdx.x, zi = threadIdx.x;
  int l = lidx(lm); int m = lm - l*l - l;
  int bin = m + 19;
  float2 acc = make_float2(0.f, 0.f);
  #pragma unroll 8
  for (int b = 0; b < 128; ++b){
    float w = w_s2[b*NLM + lm];
    float2 v = xf[((size_t)bin*128 + b)*256 + zi];
    acc.x += w*v.x; acc.y += w*v.y;
  }
  xlT[(size_t)zi*NLM + lm] = acc;
}

__global__ void k_zl2(const float2* xlT, const float2* ycT, const int* ridx, float2* zl2){
  int tid = blockIdx.x*256 + threadIdx.x;
  int zo = tid / NPACK, k = tid % NPACK;
  int info = ridx[k];
  int mj = info & 255, njs = (info>>8)&255, l = info>>16;
  int z = zo >> 5, o = zo & 31;
  int lmm = l*l + l + mj;
  int lmn = l*l + l + (njs - 19);
  float2 acc = make_float2(0.f, 0.f);
  for (int i = 0; i < 16; ++i){
    float2 a  = xlT[(size_t)(z*16 + i)*NLM + lmm];
    float2 bb = ycT[(size_t)(o*16 + i)*NLM + lmn];
    acc.x += a.x*bb.x - a.y*bb.y;
    acc.y += a.x*bb.y + a.y*bb.x;
  }
  zl2[tid] = acc;
}

// ---- synthesis stage 1: C[(zoL*40+b)][sorted pair] -------------------
// block = (zoLocal, b-quarter); zS staged once; no inner barriers
__global__ __launch_bounds__(512) void k_s1(const float2* zl2, const float* dinv2,
                                            const int* psort, float2* Cg, int zo0){
  __shared__ float2 zS[NPACK];   // 44.24 KB
  int zoL = blockIdx.x >> 2;
  int bq  = blockIdx.x & 3;
  int zo = zo0 + zoL;
  int t = threadIdx.x;
  const float2* zrow = zl2 + (size_t)zo*NPACK;
  for (int k = t; k < NPACK; k += 512) zS[k] = zrow[k];
  int pk0 = psort[t];
  int pk1 = psort[(t < NPAIR-512) ? (512+t) : 0];
  int mj0 = pk0&255, nj0 = (pk0>>8)&255;
  int mj1 = pk1&255, nj1 = (pk1>>8)&255;
  __syncthreads();
  for (int bb = 0; bb < 10; ++bb){
    int b = bq*10 + bb;
    const float* drow = dinv2 + (size_t)b*NPACK;
    float2 c0 = make_float2(0.f,0.f), c1 = c0;
    #pragma unroll
    for (int l = 0; l < 20; ++l){
      int W = 2*l+1;
      int base = loffd(l) + l - 19;     // id = base + mj*W + njs
      int np = (2*l+1)*(l+1);           // sorted-space active prefix
      if (t < np){
        int id = base + mj0*W + nj0;
        float dv = drow[id]; float2 zv = zS[id];
        c0.x += dv*zv.x; c0.y += dv*zv.y;
      }
      if (512+t < np){
        int id = base + mj1*W + nj1;
        float dv = drow[id]; float2 zv = zS[id];
        c1.x += dv*zv.x; c1.y += dv*zv.y;
      }
    }
    float2* crow = Cg + (size_t)(zoL*40 + b)*NPAIR;
    crow[t] = c0;                       // coalesced, sorted order
    if (t < NPAIR-512) crow[512+t] = c1;
  }
}

// ---- synthesis stages 2+3: per (zo,b) block, 25.1 KB LDS, 4 blocks/CU
__global__ __launch_bounds__(512) void k_s2(const float2* Cg, const int* psort,
                                            const float2* wsyn, const float* bias,
                                            float* out, int zo0){
  __shared__ float2 Cs[NPAIR];               // 6.24 KB
  __shared__ float2 Gs[800];                 // 6.4 KB
  __shared__ float2 Wns[1560];               // 12.48 KB
  int blk = blockIdx.x;                      // zoL*40 + b
  int zoL = blk / 40, b = blk % 40;
  int zo = zo0 + zoL;
  int o = zo & 31;
  int t = threadIdx.x;

  const float2* crow = Cg + (size_t)blk*NPAIR;
  {
    int pk = psort[t];
    Cs[(pk&255)*39 + ((pk>>8)&255)] = crow[t];     // LDS-side scatter
    if (t < NPAIR-512){
      int pk2 = psort[512+t];
      Cs[(pk2&255)*39 + ((pk2>>8)&255)] = crow[512+t];
    }
  }
  for (int idx = t; idx < 1560; idx += 512) Wns[idx] = wsyn[idx];
  __syncthreads();

  // stage 2: G[mj][g] = sum_n C[mj][n] * Wn[n][g]
  for (int idx = t; idx < 800; idx += 512){
    int mj = idx/40, g = idx%40;
    const float2* cr = Cs + mj*39;
    float2 acc = make_float2(0.f, 0.f);
    #pragma unroll 13
    for (int nj = 0; nj < 39; ++nj){
      float2 c = cr[nj]; float2 w = Wns[nj*40 + g];
      acc.x += c.x*w.x - c.y*w.y;
      acc.y += c.x*w.y + c.y*w.x;
    }
    Gs[idx] = acc;
  }
  __syncthreads();

  // stage 3: out[a][g] = G0[g].x + 2*sum_{mj>=1} Re(G[mj][g]*Wm[mj][a]) + bias
  if (t < 400){
    int g = t % 40, ac = t / 40;       // 4 a's per thread
    float s0=0.f, s1=0.f, s2=0.f, s3=0.f;
    for (int mj = 1; mj < 20; ++mj){
      float2 gv = Gs[mj*40 + g];
      const float2* wm = Wns + (19+mj)*40 + 4*ac;
      float2 w0 = wm[0], w1 = wm[1], w2 = wm[2], w3 = wm[3];
      s0 += gv.x*w0.x - gv.y*w0.y;
      s1 += gv.x*w1.x - gv.y*w1.y;
      s2 += gv.x*w2.x - gv.y*w2.y;
      s3 += gv.x*w3.x - gv.y*w3.y;
    }
    float g0 = Gs[g].x;
    float bv = bias[o];
    float* orow = out + ((size_t)zo*40 + b)*1600;
    orow[(4*ac+0)*40 + g] = g0 + 2.f*s0 + bv;
    orow[(4*ac+1)*40 + g] = g0 + 2.f*s1 + bv;
    orow[(4*ac+2)*40 + g] = g0 + 2.f*s2 + bv;
    orow[(4*ac+3)*40 + g] = g0 + 2.f*s3 + bv;
  }
}

extern "C" void kernel_launch(void* const* d_in, const int* in_sizes, int n_in,
                              void* d_out, int out_size, void* d_ws, size_t ws_size,
                              hipStream_t stream) {
  const float* x    = (const float*)d_in[0];
  const float* ker  = (const float*)d_in[1];
  const float* bias = (const float*)d_in[2];
  float* out = (float*)d_out;

  char* ws = (char*)d_ws;
  size_t cur = 0;
  auto alloc = [&](size_t bytes)->char*{
    char* p = ws + cur;
    cur += (bytes + 255) & ~(size_t)255;
    return p;
  };
  double* lg    = (double*)alloc(64*8);
  double* wq    = (double*)alloc(128*8);
  int*    ridx  = (int*)   alloc(NPACK*4);
  int*    psort = (int*)   alloc(NPAIR*4);
  float2* wsyn  = (float2*)alloc((size_t)1560*8);
  float*  w_s2  = (float*) alloc((size_t)NB_IN*NLM*4);
  float*  dinv2 = (float*) alloc((size_t)TWOB*NPACK*4);
  float2* Fc    = (float2*)alloc((size_t)24*NLM*8);
  float2* ycT   = (float2*)alloc((size_t)512*400*8);
  float2* xf    = (float2*)alloc((size_t)NBINS*128*256*8);
  float2* xlT   = (float2*)alloc((size_t)256*NLM*8);
  float2* zl2   = (float2*)alloc((size_t)NZO*NPACK*8);
  float2* Cg    = (float2*)alloc((size_t)128*40*NPAIR*8);   // 32 MB slice
  (void)ws_size; (void)in_sizes; (void)n_in; (void)out_size;

  k_init  <<<1, 256, 0, stream>>>(lg, wq, ridx, psort, wsyn);
  k_tables<<<73, 256, 0, stream>>>(w_s2, dinv2, Fc, ridx, lg, wq);
  k_yc    <<<800, 256, 0, stream>>>(ker, Fc, ycT);

  k_dft  <<<(256*128)/4, 256, 0, stream>>>(x, xf);
  k_xl   <<<NLM, 256, 0, stream>>>(xf, w_s2, xlT);
  k_zl2  <<<(NZO*NPACK)/256, 256, 0, stream>>>(xlT, ycT, ridx, zl2);

  for (int s = 0; s < 4; ++s){
    k_s1<<<512,  512, 0, stream>>>(zl2, dinv2, psort, Cg, s*128);
    k_s2<<<5120, 512, 0, stream>>>(Cg, psort, wsyn, bias, out, s*128);
  }
}

// Round 11
// 571.980 us; speedup vs baseline: 1.1649x; 1.0725x over previous
//
#include <hip/hip_runtime.h>
#include <math.h>

#define NB_IN   128
#define NBINS   39
#define NLM     400
#define NZO     512
#define NPAIR   780
#define NPACK   5530
#define TWOB    40
#define PI_D    3.14159265358979323846
#define SCALING 0.008164965809277261

__host__ __device__ __forceinline__ int loffd(int l){ return l*(4*l*l + 3*l - 1)/6; }

__device__ __forceinline__ int lidx(int lm){
  int l = (int)sqrtf((float)lm);
  while ((l+1)*(l+1) <= lm) ++l;
  while (l*l > lm) --l;
  return l;
}

// Wigner little-d via Jacobi sum (one-shot)
__device__ double wigner_d(int l, int m, int n, double beta, const double* lg){
  double cb = cos(0.5*beta), sb = sin(0.5*beta);
  double lcb = log(cb), lsb = log(sb);
  double pref = 0.5*(lg[l+m]+lg[l-m]+lg[l+n]+lg[l-n]);
  int s0 = 0 > (n-m) ? 0 : (n-m);
  int s1 = (l+n) < (l-m) ? (l+n) : (l-m);
  double val = 0.0;
  for (int s = s0; s <= s1; ++s){
    double c = pref - (lg[l+n-s]+lg[s]+lg[m-n+s]+lg[l-m-s]);
    double t = exp(c + (double)(2*l+n-m-2*s)*lcb + (double)(m-n+2*s)*lsb);
    val += ((m-n+s)&1) ? -t : t;
  }
  return val;
}

// fast Wigner: 2 log + 1 exp + ratio recurrence over s (fp64)
__device__ double wigner_fast(int l, int m, int n, double beta, const double* lg){
  double cb = cos(0.5*beta), sb = sin(0.5*beta);
  double lcb = log(cb), lsb = log(sb);
  double pref = 0.5*(lg[l+m]+lg[l-m]+lg[l+n]+lg[l-n]);
  int s0 = 0 > (n-m) ? 0 : (n-m);
  int s1 = (l+n) < (l-m) ? (l+n) : (l-m);
  double ratio = (sb*sb)/(cb*cb);
  double t = exp(pref - (lg[l+n-s0]+lg[s0]+lg[m-n+s0]+lg[l-m-s0])
               + (double)(2*l+n-m-2*s0)*lcb + (double)(m-n+2*s0)*lsb);
  double sgn = ((m-n+s0)&1) ? -1.0 : 1.0;
  double acc = 0.0;
  for (int s = s0; s <= s1; ++s){
    acc += sgn*t;
    sgn = -sgn;
    t *= ratio * ((double)((l+n-s)*(l-m-s)) / (double)((s+1)*(m-n+s+1)));
  }
  return acc;
}

// ---- constants: k_init (lg, wq, ridx, psort, wsyn) -------------------
__global__ void k_init(double* lg, double* wq, int* ridx, int* psort, float2* wsyn){
  int t = threadIdx.x;  // 256
  if (t == 0){
    lg[0] = 0.0; double acc = 0.0;
    for (int k = 1; k <= 40; ++k){ acc += log((double)k); lg[k] = acc; }
  }
  for (int pair = t; pair < 210; pair += 256){
    int l = (int)((sqrtf(8.f*pair+1.f)-1.f)*0.5f);
    while ((l+1)*(l+2)/2 <= pair) ++l;
    while (l*(l+1)/2 > pair) --l;
    int mj = pair - l*(l+1)/2;
    int base = loffd(l) + mj*(2*l+1);
    for (int j = 0; j < 2*l+1; ++j){
      int njs = 19-l + j;
      ridx[base+j] = mj | (njs<<8) | (l<<16);
    }
  }
  for (int p = t; p < NPAIR; p += 256){
    int mj = p/39, njs = p%39, d = njs-19, ad = d<0?-d:d;
    int lam = mj > ad ? mj : ad;
    int pre = (lam==0) ? 0 : (2*lam-1)*lam;
    int rank = (mj < lam) ? (2*mj + ((njs==19+lam)?1:0))
                          : (2*lam + (njs-(19-lam)));
    psort[pre+rank] = mj | (njs<<8);
  }
  if (t < 128){
    double theta = PI_D*(2*t+1)/256.0;
    double s = 0.0;
    for (int k = 0; k < 64; ++k) s += sin((2*k+1)*theta)/(double)(2*k+1);
    wq[t] = (2.0/64.0)*sin(theta)*s;
  }
  // wsyn[njs*40+g] = e^{i (njs-19) g 2pi/40}; Wm[mj][a] = wsyn[(19+mj)*40+a]
  for (int idx = t; idx < 1560; idx += 256){
    int njs = idx/40, g = idx%40;
    double ang = 2.0*PI_D*(double)(njs-19)*(double)g/40.0;
    wsyn[idx] = make_float2((float)cos(ang), (float)sin(ang));
  }
}

// ---- fused tables: blocks 0..12 ws2 | 13..34 dinv2(+mirror) | 35..72 Fc
__global__ void k_tables(float* w_s2, float* dinv2, float2* Fc,
                         const int* ridx, const double* lg, const double* wq){
  int bid = blockIdx.x, t = threadIdx.x;
  if (bid < 13){
    int tid = bid*256 + t;
    if (tid >= 400*8) return;
    int lm = tid >> 3, bc = tid & 7;
    int l = lidx(lm); int m = lm - l*l - l;
    for (int j = 0; j < 16; ++j){
      int b = bc*16 + j;
      double beta = PI_D*(2*b+1)/256.0;
      w_s2[b*NLM + lm] = (float)(wigner_fast(l, m, 0, beta, lg) * wq[b]);
    }
  } else if (bid < 35){
    int k = (bid-13)*256 + t;
    if (k >= NPACK) return;
    int info = ridx[k];
    int mj = info & 255, njs = (info>>8)&255, l = info>>16;
    int n = njs - 19;
    int mirror_k = loffd(l) + mj*(2*l+1) + (l + 19 - njs);
    float sgn = ((l+mj)&1) ? -1.f : 1.f;
    for (int b = 0; b < 20; ++b){
      double beta = PI_D*(2*b+1)/80.0;
      float v = (float)((double)(2*l+1) * wigner_fast(l, mj, n, beta, lg));
      dinv2[b*NPACK + k] = v;
      dinv2[(39-b)*NPACK + mirror_k] = sgn * v;   // d(pi-b) identity
    }
  } else {
    int tid = (bid-35)*256 + t;
    if (tid >= 24*NLM) return;
    int p = tid / NLM, lm = tid % NLM;
    int l = lidx(lm); int m = lm - l*l - l;
    double beta = PI_D*(double)(p/8 + 1)/24.0;
    double alpha = (double)(p%8)*(PI_D/4.0);
    double d = wigner_d(l, m, 0, beta, lg);
    double a = (double)m*alpha;            // conj(F_k)
    Fc[tid] = make_float2((float)(d*cos(a)), (float)(d*sin(a)));
  }
}

__global__ void k_yc(const float* ker, const float2* Fc, float2* ycT){
  int tid = blockIdx.x*256 + threadIdx.x;
  if (tid >= NLM*NZO) return;
  int lm = tid / 512, io = tid % 512;
  int i = io >> 5, o = io & 31;
  float2 acc = make_float2(0.f, 0.f);
  for (int p = 0; p < 24; ++p){
    float kv = ker[io*24 + p];
    float2 f = Fc[p*NLM + lm];
    acc.x += kv*f.x; acc.y += kv*f.y;
  }
  acc.x *= (float)SCALING; acc.y *= (float)SCALING;
  ycT[((size_t)(o*16 + i))*NLM + lm] = acc;
}

// ---- pipeline --------------------------------------------------------
// xf[mj][b][zi]; 4-way ILP phase recurrence
__global__ __launch_bounds__(256) void k_dft(const float* x, float2* xf){
  __shared__ float rows[4][128];
  int t = threadIdx.x, g = t >> 6, lane = t & 63;
  int r = blockIdx.x*4 + g;
  int zi = r & 255, b = r >> 8;
  const float* xr = x + ((size_t)zi*128 + b)*128;
  rows[g][lane]    = xr[lane];
  rows[g][lane+64] = xr[lane+64];
  __syncthreads();
  if (lane < NBINS){
    int m = lane - 19;
    float th = -2.0f*(float)PI_D*(float)m/128.0f;
    float sn1, cs1; sincosf(th, &sn1, &cs1);
    float cs2 = cs1*cs1 - sn1*sn1, sn2 = 2.f*cs1*sn1;
    float cs4 = cs2*cs2 - sn2*sn2, sn4 = 2.f*cs2*sn2;
    float w0r = 1.f, w0i = 0.f;
    float w1r = cs1, w1i = sn1;
    float w2r = cs2, w2i = sn2;
    float w3r = cs1*cs2 - sn1*sn2, w3i = cs1*sn2 + sn1*cs2;
    float2 a0 = make_float2(0.f,0.f), a1 = a0, a2 = a0, a3 = a0;
    const float* rw = rows[g];
    #pragma unroll 4
    for (int q = 0; q < 32; ++q){
      float v0 = rw[4*q], v1 = rw[4*q+1], v2 = rw[4*q+2], v3 = rw[4*q+3];
      a0.x += v0*w0r; a0.y += v0*w0i;
      a1.x += v1*w1r; a1.y += v1*w1i;
      a2.x += v2*w2r; a2.y += v2*w2i;
      a3.x += v3*w3r; a3.y += v3*w3i;
      float nr;
      nr = w0r*cs4 - w0i*sn4; w0i = w0r*sn4 + w0i*cs4; w0r = nr;
      nr = w1r*cs4 - w1i*sn4; w1i = w1r*sn4 + w1i*cs4; w1r = nr;
      nr = w2r*cs4 - w2i*sn4; w2i = w2r*sn4 + w2i*cs4; w2r = nr;
      nr = w3r*cs4 - w3i*sn4; w3i = w3r*sn4 + w3i*cs4; w3r = nr;
    }
    float2 acc = make_float2(a0.x+a1.x+a2.x+a3.x, a0.y+a1.y+a2.y+a3.y);
    xf[((size_t)lane*128 + b)*256 + zi] = acc;
  }
}

// xlT[zi][lm] = sum_b w_s2[b][lm] * xf[bin(lm)][b][zi]
__global__ void k_xl(const float2* xf, const float* w_s2, float2* xlT){
  int lm = blockIdx.x, zi = threadIdx.x;
  int l = lidx(lm); int m = lm - l*l - l;
  int bin = m + 19;
  float2 acc = make_float2(0.f, 0.f);
  #pragma unroll 8
  for (int b = 0; b < 128; ++b){
    float w = w_s2[b*NLM + lm];
    float2 v = xf[((size_t)bin*128 + b)*256 + zi];
    acc.x += w*v.x; acc.y += w*v.y;
  }
  xlT[(size_t)zi*NLM + lm] = acc;
}

// ---- fused zl2 + synthesis stage 1: block = zo -----------------------
// zS (zl2 row) computed in-LDS from xlT/ycT, then C for all 40 b
__global__ __launch_bounds__(512) void k_zs1(const float2* xlT, const float2* ycT,
                                             const int* ridx, const float* dinv2,
                                             const int* psort, float2* Cg){
  __shared__ float2 zS[NPACK];   // 44.24 KB
  int zo = blockIdx.x;
  int z = zo >> 5, o = zo & 31;
  int t = threadIdx.x;

  const float2* xrow = xlT + (size_t)(z*16)*NLM;
  const float2* yrow = ycT + (size_t)(o*16)*NLM;
  for (int k = t; k < NPACK; k += 512){
    int info = ridx[k];
    int mj = info & 255, njs = (info>>8)&255, l = info>>16;
    int lmm = l*l + l + mj;
    int lmn = l*l + l + njs - 19;
    float2 acc = make_float2(0.f, 0.f);
    #pragma unroll 16
    for (int i = 0; i < 16; ++i){
      float2 a  = xrow[i*NLM + lmm];
      float2 bb = yrow[i*NLM + lmn];
      acc.x += a.x*bb.x - a.y*bb.y;
      acc.y += a.x*bb.y + a.y*bb.x;
    }
    zS[k] = acc;
  }
  int pk0 = psort[t];
  int pk1 = psort[(t < NPAIR-512) ? (512+t) : 0];
  int mj0 = pk0&255, nj0 = (pk0>>8)&255;
  int mj1 = pk1&255, nj1 = (pk1>>8)&255;
  __syncthreads();

  for (int b = 0; b < 40; ++b){
    const float* drow = dinv2 + (size_t)b*NPACK;
    float2 c0 = make_float2(0.f,0.f), c1 = c0;
    #pragma unroll
    for (int l = 0; l < 20; ++l){
      int W = 2*l+1;
      int base = loffd(l) + l - 19;     // id = base + mj*W + njs
      int np = (2*l+1)*(l+1);           // sorted-space active prefix
      if (t < np){
        int id = base + mj0*W + nj0;
        float dv = drow[id]; float2 zv = zS[id];
        c0.x += dv*zv.x; c0.y += dv*zv.y;
      }
      if (512+t < np){
        int id = base + mj1*W + nj1;
        float dv = drow[id]; float2 zv = zS[id];
        c1.x += dv*zv.x; c1.y += dv*zv.y;
      }
    }
    float2* crow = Cg + (size_t)(zo*40 + b)*NPAIR;
    crow[t] = c0;                       // coalesced, sorted order
    if (t < NPAIR-512) crow[512+t] = c1;
  }
}

// ---- synthesis stages 2+3: per (zo,b) block, 25.1 KB LDS -------------
__global__ __launch_bounds__(512) void k_s2(const float2* Cg, const int* psort,
                                            const float2* wsyn, const float* bias,
                                            float* out){
  __shared__ float2 Cs[NPAIR];               // 6.24 KB
  __shared__ float2 Gs[800];                 // 6.4 KB
  __shared__ float2 Wns[1560];               // 12.48 KB
  int blk = blockIdx.x;                      // zo*40 + b
  int zo = blk / 40;
  int o = zo & 31;
  int t = threadIdx.x;

  const float2* crow = Cg + (size_t)blk*NPAIR;
  {
    int pk = psort[t];
    Cs[(pk&255)*39 + ((pk>>8)&255)] = crow[t];     // LDS-side scatter
    if (t < NPAIR-512){
      int pk2 = psort[512+t];
      Cs[(pk2&255)*39 + ((pk2>>8)&255)] = crow[512+t];
    }
  }
  for (int idx = t; idx < 1560; idx += 512) Wns[idx] = wsyn[idx];
  __syncthreads();

  // stage 2: G[mj][g] = sum_n C[mj][n] * Wn[n][g]
  for (int idx = t; idx < 800; idx += 512){
    int mj = idx/40, g = idx%40;
    const float2* cr = Cs + mj*39;
    float2 acc = make_float2(0.f, 0.f);
    #pragma unroll 13
    for (int nj = 0; nj < 39; ++nj){
      float2 c = cr[nj]; float2 w = Wns[nj*40 + g];
      acc.x += c.x*w.x - c.y*w.y;
      acc.y += c.x*w.y + c.y*w.x;
    }
    Gs[idx] = acc;
  }
  __syncthreads();

  // stage 3: out[a][g] = G0[g].x + 2*sum_{mj>=1} Re(G[mj][g]*Wm[mj][a]) + bias
  if (t < 400){
    int g = t % 40, ac = t / 40;       // 4 a's per thread
    float s0=0.f, s1=0.f, s2=0.f, s3=0.f;
    for (int mj = 1; mj < 20; ++mj){
      float2 gv = Gs[mj*40 + g];
      const float2* wm = Wns + (19+mj)*40 + 4*ac;
      float2 w0 = wm[0], w1 = wm[1], w2 = wm[2], w3 = wm[3];
      s0 += gv.x*w0.x - gv.y*w0.y;
      s1 += gv.x*w1.x - gv.y*w1.y;
      s2 += gv.x*w2.x - gv.y*w2.y;
      s3 += gv.x*w3.x - gv.y*w3.y;
    }
    float g0 = Gs[g].x;
    float bv = bias[o];
    float* orow = out + (size_t)blk*1600;
    orow[(4*ac+0)*40 + g] = g0 + 2.f*s0 + bv;
    orow[(4*ac+1)*40 + g] = g0 + 2.f*s1 + bv;
    orow[(4*ac+2)*40 + g] = g0 + 2.f*s2 + bv;
    orow[(4*ac+3)*40 + g] = g0 + 2.f*s3 + bv;
  }
}

extern "C" void kernel_launch(void* const* d_in, const int* in_sizes, int n_in,
                              void* d_out, int out_size, void* d_ws, size_t ws_size,
                              hipStream_t stream) {
  const float* x    = (const float*)d_in[0];
  const float* ker  = (const float*)d_in[1];
  const float* bias = (const float*)d_in[2];
  float* out = (float*)d_out;

  char* ws = (char*)d_ws;
  size_t cur = 0;
  auto alloc = [&](size_t bytes)->char*{
    char* p = ws + cur;
    cur += (bytes + 255) & ~(size_t)255;
    return p;
  };
  double* lg    = (double*)alloc(64*8);
  double* wq    = (double*)alloc(128*8);
  int*    ridx  = (int*)   alloc(NPACK*4);
  int*    psort = (int*)   alloc(NPAIR*4);
  float2* wsyn  = (float2*)alloc((size_t)1560*8);
  float*  w_s2  = (float*) alloc((size_t)NB_IN*NLM*4);
  float*  dinv2 = (float*) alloc((size_t)TWOB*NPACK*4);
  float2* Fc    = (float2*)alloc((size_t)24*NLM*8);
  float2* ycT   = (float2*)alloc((size_t)512*400*8);
  float2* xf    = (float2*)alloc((size_t)NBINS*128*256*8);
  float2* xlT   = (float2*)alloc((size_t)256*NLM*8);
  float2* Cg    = (float2*)alloc((size_t)NZO*40*NPAIR*8);   // 128 MB
  (void)ws_size; (void)in_sizes; (void)n_in; (void)out_size;

  k_init  <<<1, 256, 0, stream>>>(lg, wq, ridx, psort, wsyn);
  k_tables<<<73, 256, 0, stream>>>(w_s2, dinv2, Fc, ridx, lg, wq);
  k_yc    <<<800, 256, 0, stream>>>(ker, Fc, ycT);

  k_dft <<<(256*128)/4, 256, 0, stream>>>(x, xf);
  k_xl  <<<NLM, 256, 0, stream>>>(xf, w_s2, xlT);
  k_zs1 <<<NZO, 512, 0, stream>>>(xlT, ycT, ridx, dinv2, psort, Cg);
  k_s2  <<<NZO*TWOB, 512, 0, stream>>>(Cg, psort, wsyn, bias, out);
}